// Round 13
// baseline (329.607 us; speedup 1.0000x reference)
//
#include <hip/hip_runtime.h>
#include <hip/hip_bf16.h>
#include <math.h>

typedef unsigned short u16;
typedef unsigned int u32;
typedef __attribute__((ext_vector_type(8))) short short8v;   // 8 bf16 = 4 VGPR
typedef __attribute__((ext_vector_type(4))) float f32x4;
typedef __attribute__((ext_vector_type(16))) float f32x16;

#define BB 2
#define TT 2048
#define DD 768
#define HH 12
#define DHH 64
#define MM 4096      // BB*TT
#define NSLOT 36     // kv-split chunks per bh: sum over qt256 of (qt+1)
#define QSC 0.18033688f   // 0.125 * log2(e): folded into Q at projection

// XOR swizzle for the GEMM's row-major [r][128B] LDS tiles (read side).
#define SWZ(r, kb) (((r) * 128) + ((kb) ^ (((r) & 7) << 4)))

typedef __attribute__((address_space(1))) void gas_void;
typedef __attribute__((address_space(3))) void las_void;
#define GLL(g, l) __builtin_amdgcn_global_load_lds((gas_void*)(g), (las_void*)(l), 16, 0, 0)

// LPT slot tables (256-row q tiles, 4-kt-tile chunks, all chunks full):
// full-weight interior chunks first (qt desc), half-weight diagonal chunks last.
__device__ const unsigned char SLOT_QT[36] = {
    7,7,7,7,7,7,7, 6,6,6,6,6,6, 5,5,5,5,5, 4,4,4,4, 3,3,3, 2,2, 1,
    7,6,5,4,3,2,1,0};
__device__ const unsigned char SLOT_C[36] = {
    0,1,2,3,4,5,6, 0,1,2,3,4,5, 0,1,2,3,4, 0,1,2,3, 0,1,2, 0,1, 0,
    7,6,5,4,3,2,1,0};
// combine lookup: interior chunks of qt at BASEF[qt]..+qt-1, diagonal at 35-qt
__device__ const unsigned char BASEF[8] = {0, 27, 25, 22, 18, 13, 7, 0};

__device__ __forceinline__ u16 f2bf(float f) {
    union { float f; unsigned u; } v; v.f = f;
    unsigned r = v.u + 0x7fff + ((v.u >> 16) & 1);   // RNE
    return (u16)(r >> 16);
}
__device__ __forceinline__ u32 pkpair(float a, float b) {   // low=a, high=b
    union { __hip_bfloat162 h; u32 u; } v;
    v.h = __float22bfloat162_rn(make_float2(a, b));
    return v.u;
}
__device__ __forceinline__ float fexp2(float x) {
#if __has_builtin(__builtin_amdgcn_exp2f)
    return __builtin_amdgcn_exp2f(x);
#else
    return exp2f(x);
#endif
}
__device__ __forceinline__ float bfhi(u32 p) {
    union { u32 u; float f; } v; v.u = p & 0xffff0000u; return v.f;
}
__device__ __forceinline__ float bflo(u32 p) {
    union { u32 u; float f; } v; v.u = p << 16; return v.f;
}

// ---------------------------------------------------------------------------
// Fused prep: blocks [0,3072) convert x fp32->bf16 (one float4/thread);
// blocks [3072,3648) transpose W [K][N] fp32 -> Wt [N][K] bf16 (64x64 tiles).
// ---------------------------------------------------------------------------
__global__ __launch_bounds__(256) void prep(
    const float* __restrict__ x, u16* __restrict__ xb,
    const float* __restrict__ W0, const float* __restrict__ W1,
    const float* __restrict__ W2, const float* __restrict__ W3,
    u16* __restrict__ T0, u16* __restrict__ T1,
    u16* __restrict__ T2, u16* __restrict__ T3)
{
    __shared__ float tile[64][65];
    const int bid = blockIdx.x;
    const int t = threadIdx.x;

    if (bid < 3072) {
        const int i = bid * 256 + t;
        const float4 v = ((const float4*)x)[i];
        union { u16 s[4]; uint2 u; } o;
        o.s[0] = f2bf(v.x); o.s[1] = f2bf(v.y); o.s[2] = f2bf(v.z); o.s[3] = f2bf(v.w);
        ((uint2*)xb)[i] = o.u;
        return;
    }

    const int idx = bid - 3072;
    const int z = idx / 144;
    const int r2 = idx - z * 144;
    const int k0 = (r2 / 12) * 64, n0 = (r2 % 12) * 64;
    const float* __restrict__ W = (z == 0) ? W0 : (z == 1) ? W1 : (z == 2) ? W2 : W3;
    u16* __restrict__ T = (z == 0) ? T0 : (z == 1) ? T1 : (z == 2) ? T2 : T3;

    const int rr = t >> 4, c4 = (t & 15) * 4;
    #pragma unroll
    for (int j = 0; j < 4; ++j) {
        const int r = rr + j * 16;
        const float4 v = *(const float4*)&W[(size_t)(k0 + r) * DD + n0 + c4];
        tile[r][c4 + 0] = v.x; tile[r][c4 + 1] = v.y;
        tile[r][c4 + 2] = v.z; tile[r][c4 + 3] = v.w;
    }
    __syncthreads();
    #pragma unroll
    for (int j = 0; j < 4; ++j) {
        const int r = rr + j * 16;
        union { u16 s[4]; uint2 u; } o;
        #pragma unroll
        for (int jj = 0; jj < 4; ++jj) o.s[jj] = f2bf(tile[c4 + jj][r]);
        *(uint2*)&T[(size_t)(n0 + r) * DD + k0 + c4] = o.u;
    }
}

// ---------------------------------------------------------------------------
// bf16 MFMA GEMM for QKV, B^T input. 128x128, BK=64, 4 waves. DOUBLE-BUFFERED
// GLL staging + SWZ reads (R8-proven). 1-D grid 576 with bijective XCD
// swizzle, m-major decode (R12-proven).
// mode 0: Q row-major [bh][t][d], PRE-SCALED by QSC
// mode 1: K subtiled  [bh][kt][j=d>>3][krow=t&63][e=d&7]
// mode 2: V subtiled  [bh][kt][j=(t>>3)&7][d][e=t&7]
// ---------------------------------------------------------------------------
__global__ __launch_bounds__(256) void gemm_bt(
    const u16* __restrict__ A,
    const u16* __restrict__ Bt0, const u16* __restrict__ Bt1, const u16* __restrict__ Bt2,
    const float* __restrict__ b0, const float* __restrict__ b1, const float* __restrict__ b2,
    u16* __restrict__ oQ, u16* __restrict__ oK, u16* __restrict__ oVt)
{
    // XCD swizzle (576 % 8 == 0 -> bijective), then m-major decode
    const int lin = blockIdx.x;
    const int cpx = gridDim.x >> 3;                 // 72
    const int swz = (lin & 7) * cpx + (lin >> 3);
    const int mt  = swz / 18;                       // 0..31 m-tile
    const int r18 = swz - mt * 18;
    const int mode = r18 / 6;                       // 0..2
    const int m0 = mt * 128, n0 = (r18 - mode * 6) * 128;

    const u16* __restrict__ Bt = (mode == 1) ? Bt1 : (mode == 2) ? Bt2 : Bt0;
    const float* __restrict__ bias = (mode == 1) ? b1 : (mode == 2) ? b2 : b0;

    __shared__ __attribute__((aligned(16))) unsigned char AsB[2][16384];
    __shared__ __attribute__((aligned(16))) unsigned char BsB[2][16384];

    const int tid = threadIdx.x, lane = tid & 63, w = tid >> 6;
    const int wr = w >> 1, wc = w & 1;
    const int lr = lane >> 4, lc = lane & 15;
    const int srcoff = 16 * ((lane & 7) ^ (lane >> 3));   // inverse swizzle

#define GSTAGE(k0_, bufi) do {                                                 \
        _Pragma("unroll")                                                      \
        for (int i_ = 0; i_ < 4; ++i_) {                                       \
            const int r_ = w * 32 + i_ * 8 + (lane >> 3);                      \
            GLL((const char*)A  + ((size_t)(m0 + r_) * DD + (k0_)) * 2 + srcoff,\
                (char*)AsB[bufi] + w * 4096 + i_ * 1024);                      \
            GLL((const char*)Bt + ((size_t)(n0 + r_) * DD + (k0_)) * 2 + srcoff,\
                (char*)BsB[bufi] + w * 4096 + i_ * 1024);                      \
        }                                                                      \
    } while (0)

    f32x4 acc[4][4];
    #pragma unroll
    for (int m = 0; m < 4; ++m)
        #pragma unroll
        for (int n = 0; n < 4; ++n) acc[m][n] = (f32x4){0.f, 0.f, 0.f, 0.f};

    GSTAGE(0, 0);
    __syncthreads();

    int cur = 0;
    #pragma unroll 1
    for (int k0 = 0; k0 < DD; k0 += 64) {
        if (k0 + 64 < DD) GSTAGE(k0 + 64, cur ^ 1);

        #pragma unroll
        for (int s = 0; s < 2; ++s) {
            short8v af[4], bf[4];
            #pragma unroll
            for (int m = 0; m < 4; ++m)
                af[m] = *(const short8v*)((const char*)AsB[cur] +
                         SWZ(wr * 64 + m * 16 + lc, s * 64 + lr * 16));
            #pragma unroll
            for (int n = 0; n < 4; ++n)
                bf[n] = *(const short8v*)((const char*)BsB[cur] +
                         SWZ(wc * 64 + n * 16 + lc, s * 64 + lr * 16));
            #pragma unroll
            for (int m = 0; m < 4; ++m)
                #pragma unroll
                for (int n = 0; n < 4; ++n)
                    acc[m][n] = __builtin_amdgcn_mfma_f32_16x16x32_bf16(
                        af[m], bf[n], acc[m][n], 0, 0, 0);
        }

        __syncthreads();   // drains prefetch; all waves done reading buf[cur]
        cur ^= 1;
    }
#undef GSTAGE

    #pragma unroll
    for (int n = 0; n < 4; ++n) {
        const int ng = n0 + wc * 64 + n * 16 + lc;
        const float bv = bias[ng];
        #pragma unroll
        for (int m = 0; m < 4; ++m) {
            const int mg0 = m0 + wr * 64 + m * 16 + lr * 4;
            if (mode == 2) {
                const int bb = mg0 >> 11, tp = mg0 & 2047;
                const int h = ng >> 6, d = ng & 63;
                const size_t idx = (size_t)(bb * HH + h) * (TT * DHH)
                                 + (tp >> 6) * 4096 + ((tp >> 3) & 7) * 512
                                 + d * 8 + (tp & 7);
                union { u16 s[4]; uint2 u; } o;
                #pragma unroll
                for (int r = 0; r < 4; ++r) o.s[r] = f2bf(acc[m][n][r] + bv);
                *(uint2*)&oVt[idx] = o.u;
            } else if (mode == 1) {
                const int h = ng >> 6, d = ng & 63;
                #pragma unroll
                for (int r = 0; r < 4; ++r) {
                    const int mg = mg0 + r;
                    const int bb = mg >> 11, tp = mg & 2047;
                    oK[(size_t)(bb * HH + h) * (TT * DHH)
                       + (tp >> 6) * 4096 + (d >> 3) * 512 + (tp & 63) * 8 + (d & 7)] =
                        f2bf(acc[m][n][r] + bv);
                }
            } else {
                const int h = ng >> 6, d = ng & 63;
                #pragma unroll
                for (int r = 0; r < 4; ++r) {
                    const int mg = mg0 + r;
                    const int bb = mg >> 11, tp = mg & 2047;
                    oQ[((size_t)(bb * HH + h) * TT + tp) * DHH + d] =
                        f2bf((acc[m][n][r] + bv) * QSC);
                }
            }
        }
    }
}

// ---------------------------------------------------------------------------
// Output projection GEMM, 64x128 tiles (R12-proven). XCD swizzle (384%8==0).
// ---------------------------------------------------------------------------
__global__ __launch_bounds__(256) void gemm_out64(
    const u16* __restrict__ A, const u16* __restrict__ Bt,
    const float* __restrict__ bias, float* __restrict__ oF)
{
    const int lin = blockIdx.x;
    const int cpx = gridDim.x >> 3;                 // 48
    const int swz = (lin & 7) * cpx + (lin >> 3);
    const int m0 = (swz / 6) * 64;                  // 64 m-tiles
    const int n0 = (swz % 6) * 128;

    __shared__ __attribute__((aligned(16))) unsigned char AsB[2][8192];
    __shared__ __attribute__((aligned(16))) unsigned char BsB[2][16384];

    const int tid = threadIdx.x, lane = tid & 63, w = tid >> 6;
    const int wr = w >> 1, wc = w & 1;
    const int lr = lane >> 4, lc = lane & 15;
    const int srcoff = 16 * ((lane & 7) ^ (lane >> 3));

#define GSTAGE(k0_, bufi) do {                                                 \
        _Pragma("unroll")                                                      \
        for (int i_ = 0; i_ < 2; ++i_) {                                       \
            const int ra_ = w * 16 + i_ * 8 + (lane >> 3);                     \
            GLL((const char*)A  + ((size_t)(m0 + ra_) * DD + (k0_)) * 2 + srcoff,\
                (char*)AsB[bufi] + w * 2048 + i_ * 1024);                      \
        }                                                                      \
        _Pragma("unroll")                                                      \
        for (int i_ = 0; i_ < 4; ++i_) {                                       \
            const int rb_ = w * 32 + i_ * 8 + (lane >> 3);                     \
            GLL((const char*)Bt + ((size_t)(n0 + rb_) * DD + (k0_)) * 2 + srcoff,\
                (char*)BsB[bufi] + w * 4096 + i_ * 1024);                      \
        }                                                                      \
    } while (0)

    f32x4 acc[2][4];
    #pragma unroll
    for (int m = 0; m < 2; ++m)
        #pragma unroll
        for (int n = 0; n < 4; ++n) acc[m][n] = (f32x4){0.f, 0.f, 0.f, 0.f};

    GSTAGE(0, 0);
    __syncthreads();

    int cur = 0;
    #pragma unroll 1
    for (int k0 = 0; k0 < DD; k0 += 64) {
        if (k0 + 64 < DD) GSTAGE(k0 + 64, cur ^ 1);

        #pragma unroll
        for (int s = 0; s < 2; ++s) {
            short8v af[2], bf[4];
            #pragma unroll
            for (int m = 0; m < 2; ++m)
                af[m] = *(const short8v*)((const char*)AsB[cur] +
                         SWZ(wr * 32 + m * 16 + lc, s * 64 + lr * 16));
            #pragma unroll
            for (int n = 0; n < 4; ++n)
                bf[n] = *(const short8v*)((const char*)BsB[cur] +
                         SWZ(wc * 64 + n * 16 + lc, s * 64 + lr * 16));
            #pragma unroll
            for (int m = 0; m < 2; ++m)
                #pragma unroll
                for (int n = 0; n < 4; ++n)
                    acc[m][n] = __builtin_amdgcn_mfma_f32_16x16x32_bf16(
                        af[m], bf[n], acc[m][n], 0, 0, 0);
        }

        __syncthreads();
        cur ^= 1;
    }
#undef GSTAGE

    #pragma unroll
    for (int n = 0; n < 4; ++n) {
        const int ng = n0 + wc * 64 + n * 16 + lc;
        const float bv = bias[ng];
        #pragma unroll
        for (int m = 0; m < 2; ++m) {
            const int mg0 = m0 + wr * 32 + m * 16 + lr * 4;
            #pragma unroll
            for (int r = 0; r < 4; ++r)
                oF[(size_t)(mg0 + r) * DD + ng] = acc[m][n][r] + bv;
        }
    }
}

// ---------------------------------------------------------------------------
// KV-split MFMA flash attention partial + FUSED COMBINE.
// Main body = R9/R12 exact (92 VGPR, 2 blocks/CU, one-shot 64KB staging, one
// barrier). After writing partials, each block: threadfence -> syncthreads ->
// tid0 atomicAdd ticket[bh*8+qt]; the LAST of the (qt+1) chunk blocks runs
// the combine (fence-acquire, fixed slot order -> bitwise-deterministic
// output) and writes ctx. Removes the attn_combine kernel + its graph gap.
// grid = 864 = 36 LPT slots * 24 bh; bid%24 = bh -> per-bh XCD affinity.
// ---------------------------------------------------------------------------
__global__ __launch_bounds__(512) void attn_fwd(
    const u16* __restrict__ qb, const u16* __restrict__ kbf,
    const u16* __restrict__ vtb, u16* __restrict__ partO,
    float* __restrict__ partL, u16* __restrict__ ctx,
    int* __restrict__ tickets)
{
    __shared__ __attribute__((aligned(16))) unsigned char smem[65536];
    __shared__ int lastflag;
    // K tile t @ t*8192 ; V tile t @ 32768 + t*8192

    const int bid = blockIdx.x;
    const int sp = bid / 24;
    const int bh = bid - sp * 24;
    const int qt = SLOT_QT[sp], c = SLOT_C[sp];
    const int kts = c * 4;

    const int tid = threadIdx.x, lane = tid & 63, w = tid >> 6;   // w 0..7
    const int l31 = lane & 31, hi = lane >> 5;

    // stage the whole chunk: 4 K tiles + 4 V tiles, 1 GLL each per thread
    {
        const char* kbase = (const char*)kbf + (size_t)bh * (TT * DHH * 2)
                          + (size_t)kts * 8192;
        const char* vbase = (const char*)vtb + (size_t)bh * (TT * DHH * 2)
                          + (size_t)kts * 8192;
        const int off = w * 1024;
        #pragma unroll
        for (int t = 0; t < 4; ++t) {
            GLL(kbase + t * 8192 + off + lane * 16,
                (char*)smem + t * 8192 + off);
            GLL(vbase + t * 8192 + off + lane * 16,
                (char*)smem + 32768 + t * 8192 + off);
        }
    }

    // Q fragments (pre-scaled at projection): row = qt*256 + w*32 + l31
    short8v aq[4];
    {
        const u16* qrow = qb + ((size_t)bh * TT + qt * 256 + w * 32 + l31) * DHH;
        #pragma unroll
        for (int s4 = 0; s4 < 4; ++s4)
            aq[s4] = *(const short8v*)(qrow + s4 * 16 + hi * 8);
    }

    f32x16 accO[2];
    #pragma unroll
    for (int i = 0; i < 16; ++i) { accO[0][i] = 0.f; accO[1][i] = 0.f; }
    float lreg = 0.f;

    __syncthreads();   // single barrier: drains GLLs, LDS read-only afterwards

    const int qmin = qt * 256 + w * 32;
    #pragma unroll
    for (int t = 0; t < 4; ++t) {
        const int kt = kts + t;
        if (kt * 64 <= qmin + 31) {   // wave has >=1 unmasked key in this tile
            const unsigned char* Kb = smem + t * 8192;
            const unsigned char* Vb = smem + 32768 + t * 8192;

            // S^T = K * Q^T (scores in log2 units via Q prescale)
            f32x16 st[2];
            #pragma unroll
            for (int i = 0; i < 16; ++i) { st[0][i] = 0.f; st[1][i] = 0.f; }
            __builtin_amdgcn_s_setprio(1);
            #pragma unroll
            for (int s4 = 0; s4 < 4; ++s4) {
                #pragma unroll
                for (int kf = 0; kf < 2; ++kf) {
                    const short8v ak = *(const short8v*)(Kb +
                        (s4 * 2 + hi) * 1024 + (kf * 32 + l31) * 16);
                    st[kf] = __builtin_amdgcn_mfma_f32_32x32x16_bf16(ak, aq[s4], st[kf], 0, 0, 0);
                }
            }
            __builtin_amdgcn_s_setprio(0);

            if (kt * 64 + 63 > qmin) {   // partial-diagonal tile: mask
                const int rowrel = qmin + l31 - kt * 64;   // q col = l31
                #pragma unroll
                for (int kf = 0; kf < 2; ++kf)
                    #pragma unroll
                    for (int reg = 0; reg < 16; ++reg) {
                        const int kloc = kf * 32 + (reg & 3) + 8 * (reg >> 2) + 4 * hi;
                        if (kloc > rowrel) st[kf][reg] = -3.0e38f;
                    }
            }

            // p = exp2(s); tree-summed row sum (no max tracking)
            float rs4[4] = {0.f, 0.f, 0.f, 0.f};
            #pragma unroll
            for (int kf = 0; kf < 2; ++kf)
                #pragma unroll
                for (int reg = 0; reg < 16; ++reg) {
                    const float p = fexp2(st[kf][reg]);
                    st[kf][reg] = p;
                    rs4[reg & 3] += p;
                }
            float rs = (rs4[0] + rs4[1]) + (rs4[2] + rs4[3]);
            {   // cross-half add via permlane32_swap (no ds_bpermute)
                u32 a, b;
                union { float f; u32 u; } cv; cv.f = rs;
                a = cv.u; b = cv.u;
                asm volatile("v_permlane32_swap_b32 %0, %1" : "+v"(a), "+v"(b));
                union { u32 u; float f; } pa, pb; pa.u = a; pb.u = b;
                const float partner = hi ? pa.f : pb.f;
                rs += partner;
            }
            lreg += rs;

            // pack P -> A-frags via cvt_pk + permlane32_swap, accumulate PV
            __builtin_amdgcn_s_setprio(1);
            #pragma unroll
            for (int ka = 0; ka < 4; ++ka) {
                const int kf = ka >> 1;
                const int rb0 = 4 * ((ka & 1) * 2);       // hi_dst = 0 reg block
                const int rb1 = 4 * ((ka & 1) * 2 + 1);   // hi_dst = 1 reg block
                u32 P0 = pkpair(st[kf][rb0 + 0], st[kf][rb0 + 1]);
                u32 P1 = pkpair(st[kf][rb0 + 2], st[kf][rb0 + 3]);
                u32 Q0 = pkpair(st[kf][rb1 + 0], st[kf][rb1 + 1]);
                u32 Q1 = pkpair(st[kf][rb1 + 2], st[kf][rb1 + 3]);
                asm volatile("v_permlane32_swap_b32 %0, %1" : "+v"(P0), "+v"(Q0));
                asm volatile("v_permlane32_swap_b32 %0, %1" : "+v"(P1), "+v"(Q1));
                union { u32 wd[4]; short8v v; } u;
                u.wd[0] = P0; u.wd[1] = P1; u.wd[2] = Q0; u.wd[3] = Q1;
                #pragma unroll
                for (int dc = 0; dc < 2; ++dc) {
                    const short8v bv = *(const short8v*)(Vb +
                        (ka * 2 + hi) * 1024 + (dc * 32 + l31) * 16);
                    accO[dc] = __builtin_amdgcn_mfma_f32_32x32x16_bf16(u.v, bv, accO[dc], 0, 0, 0);
                }
            }
            __builtin_amdgcn_s_setprio(0);
        }
    }

    // store partials (O bf16 unnormalized, l f32)
    const int gslot = bh * NSLOT + sp;
    if (hi == 0)
        partL[(size_t)gslot * 256 + w * 32 + l31] = lreg;
    u16* po = partO + (size_t)gslot * 16384;
    #pragma unroll
    for (int reg = 0; reg < 16; ++reg) {
        const int qrow = (reg & 3) + 8 * (reg >> 2) + 4 * hi;
        #pragma unroll
        for (int dc = 0; dc < 2; ++dc)
            po[(w * 32 + qrow) * 64 + dc * 32 + l31] = f2bf(accO[dc][reg]);
    }

    // -------- fused combine: last chunk block for (bh,qt) merges all --------
    __threadfence();                 // release: partials visible device-wide
    __syncthreads();                 // all threads' fences done
    if (tid == 0) {
        const int old = atomicAdd(&tickets[bh * 8 + qt], 1);
        lastflag = (old == qt);      // nc = qt+1 chunks
    }
    __syncthreads();
    if (!lastflag) return;

    __threadfence();                 // acquire: see other blocks' partials
    {
        const int b2 = bh / HH, h2 = bh - b2 * HH;
        const int q = tid >> 1, half = tid & 1;

        float lsum = 0.f;
        float acc[32];
        #pragma unroll
        for (int j = 0; j < 32; ++j) acc[j] = 0.f;

#define ACCUM(gs) do {                                                         \
        lsum += partL[(size_t)(gs) * 256 + q];                                 \
        const u16* po_ = partO + (size_t)(gs) * 16384 + q * 64 + half * 32;    \
        _Pragma("unroll")                                                      \
        for (int v_ = 0; v_ < 4; ++v_) {                                       \
            const uint4 pk = *(const uint4*)(po_ + v_ * 8);                    \
            acc[v_*8+0] += bflo(pk.x); acc[v_*8+1] += bfhi(pk.x);              \
            acc[v_*8+2] += bflo(pk.y); acc[v_*8+3] += bfhi(pk.y);              \
            acc[v_*8+4] += bflo(pk.z); acc[v_*8+5] += bfhi(pk.z);              \
            acc[v_*8+6] += bflo(pk.w); acc[v_*8+7] += bfhi(pk.w);              \
        }                                                                      \
    } while (0)

        const int basef = bh * NSLOT + BASEF[qt];
        #pragma unroll 1
        for (int cc = 0; cc < qt; ++cc) ACCUM(basef + cc);
        ACCUM(bh * NSLOT + (35 - qt));        // diagonal chunk
#undef ACCUM

        const float inv = 1.f / lsum;
        u16* dst = ctx + (size_t)(b2 * TT + qt * 256 + q) * DD + h2 * 64 + half * 32;
        #pragma unroll
        for (int v = 0; v < 4; ++v) {
            uint4 o;
            o.x = pkpair(acc[v*8+0] * inv, acc[v*8+1] * inv);
            o.y = pkpair(acc[v*8+2] * inv, acc[v*8+3] * inv);
            o.z = pkpair(acc[v*8+4] * inv, acc[v*8+5] * inv);
            o.w = pkpair(acc[v*8+6] * inv, acc[v*8+7] * inv);
            *(uint4*)(dst + v * 8) = o;
        }
    }
}

extern "C" void kernel_launch(void* const* d_in, const int* in_sizes, int n_in,
                              void* d_out, int out_size, void* d_ws, size_t ws_size,
                              hipStream_t stream) {
    (void)in_sizes; (void)n_in; (void)out_size; (void)ws_size;
    const float* x  = (const float*)d_in[0];
    const float* Wq = (const float*)d_in[1];
    const float* bq = (const float*)d_in[2];
    const float* Wk = (const float*)d_in[3];
    const float* bk = (const float*)d_in[4];
    const float* Wv = (const float*)d_in[5];
    const float* bv = (const float*)d_in[6];
    const float* Wo = (const float*)d_in[7];
    const float* bo = (const float*)d_in[8];
    float* out = (float*)d_out;

    u16* xb    = (u16*)d_ws;
    u16* WtQ   = xb + (size_t)MM * DD;
    u16* WtK   = WtQ + (size_t)DD * DD;
    u16* WtV   = WtK + (size_t)DD * DD;
    u16* WtO   = WtV + (size_t)DD * DD;
    u16* qbuf  = WtO + (size_t)DD * DD;      // [bh][t][d] row-major, pre-scaled
    u16* kbuf  = qbuf + (size_t)MM * DD;     // [bh][kt][j][krow][e] subtiled
    u16* vtbuf = kbuf + (size_t)MM * DD;     // [bh][kt][j][d][e]   subtiled
    u16* ctxb  = vtbuf + (size_t)MM * DD;    // [b*t][768]
    u16* pO    = ctxb + (size_t)MM * DD;     // 864 slots * 16384 bf16
    float* pL  = (float*)(pO + (size_t)24 * NSLOT * 16384);  // 864 * 256 f32
    int* tickets = (int*)(pL + (size_t)24 * NSLOT * 256);    // 24*8 ints

    hipMemsetAsync(tickets, 0, 24 * 8 * sizeof(int), stream);
    prep<<<dim3(3648), 256, 0, stream>>>(x, xb, Wq, Wk, Wv, Wo, WtQ, WtK, WtV, WtO);
    gemm_bt<<<dim3(576), 256, 0, stream>>>(xb, WtQ, WtK, WtV, bq, bk, bv,
                                           qbuf, kbuf, vtbuf);
    attn_fwd<<<dim3(24 * NSLOT), 512, 0, stream>>>(qbuf, kbuf, vtbuf, pO, pL,
                                                   ctxb, tickets);
    gemm_out64<<<dim3(384), 256, 0, stream>>>(ctxb, WtO, bo, out);
}

// Round 14
// 86.861 us; speedup vs baseline: 3.7947x; 3.7947x over previous
//
#include <hip/hip_runtime.h>
#include <hip/hip_bf16.h>
#include <math.h>

typedef unsigned short u16;
typedef unsigned int u32;
typedef __attribute__((ext_vector_type(8))) short short8v;   // 8 bf16 = 4 VGPR
typedef __attribute__((ext_vector_type(4))) float f32x4;
typedef __attribute__((ext_vector_type(16))) float f32x16;

#define BB 2
#define TT 2048
#define DD 768
#define HH 12
#define DHH 64
#define MM 4096      // BB*TT
#define NSLOT 36     // kv-split chunks per bh: sum over qt256 of (qt+1)
#define QSC 0.18033688f   // 0.125 * log2(e): folded into Q at projection

// XOR swizzle for the GEMM's row-major [r][128B] LDS tiles (read side).
#define SWZ(r, kb) (((r) * 128) + ((kb) ^ (((r) & 7) << 4)))

typedef __attribute__((address_space(1))) void gas_void;
typedef __attribute__((address_space(3))) void las_void;
#define GLL(g, l) __builtin_amdgcn_global_load_lds((gas_void*)(g), (las_void*)(l), 16, 0, 0)

// LPT slot tables (256-row q tiles, 4-kt-tile chunks, all chunks full):
// full-weight interior chunks first (qt desc), half-weight diagonal chunks last.
__device__ const unsigned char SLOT_QT[36] = {
    7,7,7,7,7,7,7, 6,6,6,6,6,6, 5,5,5,5,5, 4,4,4,4, 3,3,3, 2,2, 1,
    7,6,5,4,3,2,1,0};
__device__ const unsigned char SLOT_C[36] = {
    0,1,2,3,4,5,6, 0,1,2,3,4,5, 0,1,2,3,4, 0,1,2,3, 0,1,2, 0,1, 0,
    7,6,5,4,3,2,1,0};
// combine lookup: interior chunks of qt at BASEF[qt]..+qt-1, diagonal at 35-qt
__device__ const unsigned char BASEF[8] = {0, 27, 25, 22, 18, 13, 7, 0};

__device__ __forceinline__ u16 f2bf(float f) {
    union { float f; unsigned u; } v; v.f = f;
    unsigned r = v.u + 0x7fff + ((v.u >> 16) & 1);   // RNE
    return (u16)(r >> 16);
}
__device__ __forceinline__ u32 pkpair(float a, float b) {   // low=a, high=b
    union { __hip_bfloat162 h; u32 u; } v;
    v.h = __float22bfloat162_rn(make_float2(a, b));
    return v.u;
}
__device__ __forceinline__ float fexp2(float x) {
#if __has_builtin(__builtin_amdgcn_exp2f)
    return __builtin_amdgcn_exp2f(x);
#else
    return exp2f(x);
#endif
}
__device__ __forceinline__ float bfhi(u32 p) {
    union { u32 u; float f; } v; v.u = p & 0xffff0000u; return v.f;
}
__device__ __forceinline__ float bflo(u32 p) {
    union { u32 u; float f; } v; v.u = p << 16; return v.f;
}

// ---------------------------------------------------------------------------
// Fused prep: blocks [0,3072) convert x fp32->bf16 (one float4/thread);
// blocks [3072,3648) transpose W [K][N] fp32 -> Wt [N][K] bf16 (64x64 tiles).
// ---------------------------------------------------------------------------
__global__ __launch_bounds__(256) void prep(
    const float* __restrict__ x, u16* __restrict__ xb,
    const float* __restrict__ W0, const float* __restrict__ W1,
    const float* __restrict__ W2, const float* __restrict__ W3,
    u16* __restrict__ T0, u16* __restrict__ T1,
    u16* __restrict__ T2, u16* __restrict__ T3)
{
    __shared__ float tile[64][65];
    const int bid = blockIdx.x;
    const int t = threadIdx.x;

    if (bid < 3072) {
        const int i = bid * 256 + t;
        const float4 v = ((const float4*)x)[i];
        union { u16 s[4]; uint2 u; } o;
        o.s[0] = f2bf(v.x); o.s[1] = f2bf(v.y); o.s[2] = f2bf(v.z); o.s[3] = f2bf(v.w);
        ((uint2*)xb)[i] = o.u;
        return;
    }

    const int idx = bid - 3072;
    const int z = idx / 144;
    const int r2 = idx - z * 144;
    const int k0 = (r2 / 12) * 64, n0 = (r2 % 12) * 64;
    const float* __restrict__ W = (z == 0) ? W0 : (z == 1) ? W1 : (z == 2) ? W2 : W3;
    u16* __restrict__ T = (z == 0) ? T0 : (z == 1) ? T1 : (z == 2) ? T2 : T3;

    const int rr = t >> 4, c4 = (t & 15) * 4;
    #pragma unroll
    for (int j = 0; j < 4; ++j) {
        const int r = rr + j * 16;
        const float4 v = *(const float4*)&W[(size_t)(k0 + r) * DD + n0 + c4];
        tile[r][c4 + 0] = v.x; tile[r][c4 + 1] = v.y;
        tile[r][c4 + 2] = v.z; tile[r][c4 + 3] = v.w;
    }
    __syncthreads();
    #pragma unroll
    for (int j = 0; j < 4; ++j) {
        const int r = rr + j * 16;
        union { u16 s[4]; uint2 u; } o;
        #pragma unroll
        for (int jj = 0; jj < 4; ++jj) o.s[jj] = f2bf(tile[c4 + jj][r]);
        *(uint2*)&T[(size_t)(n0 + r) * DD + k0 + c4] = o.u;
    }
}

// ---------------------------------------------------------------------------
// bf16 MFMA GEMM for QKV, B^T input. 128x128, BK=64, 4 waves. DOUBLE-BUFFERED
// GLL staging + SWZ reads (R8-proven). 1-D grid 576 with bijective XCD
// swizzle, m-major decode (R12-proven).
// mode 0: Q row-major [bh][t][d], PRE-SCALED by QSC
// mode 1: K subtiled  [bh][kt][j=d>>3][krow=t&63][e=d&7]
// mode 2: V subtiled  [bh][kt][j=(t>>3)&7][d][e=t&7]
// ---------------------------------------------------------------------------
__global__ __launch_bounds__(256) void gemm_bt(
    const u16* __restrict__ A,
    const u16* __restrict__ Bt0, const u16* __restrict__ Bt1, const u16* __restrict__ Bt2,
    const float* __restrict__ b0, const float* __restrict__ b1, const float* __restrict__ b2,
    u16* __restrict__ oQ, u16* __restrict__ oK, u16* __restrict__ oVt)
{
    // XCD swizzle (576 % 8 == 0 -> bijective), then m-major decode
    const int lin = blockIdx.x;
    const int cpx = gridDim.x >> 3;                 // 72
    const int swz = (lin & 7) * cpx + (lin >> 3);
    const int mt  = swz / 18;                       // 0..31 m-tile
    const int r18 = swz - mt * 18;
    const int mode = r18 / 6;                       // 0..2
    const int m0 = mt * 128, n0 = (r18 - mode * 6) * 128;

    const u16* __restrict__ Bt = (mode == 1) ? Bt1 : (mode == 2) ? Bt2 : Bt0;
    const float* __restrict__ bias = (mode == 1) ? b1 : (mode == 2) ? b2 : b0;

    __shared__ __attribute__((aligned(16))) unsigned char AsB[2][16384];
    __shared__ __attribute__((aligned(16))) unsigned char BsB[2][16384];

    const int tid = threadIdx.x, lane = tid & 63, w = tid >> 6;
    const int wr = w >> 1, wc = w & 1;
    const int lr = lane >> 4, lc = lane & 15;
    const int srcoff = 16 * ((lane & 7) ^ (lane >> 3));   // inverse swizzle

#define GSTAGE(k0_, bufi) do {                                                 \
        _Pragma("unroll")                                                      \
        for (int i_ = 0; i_ < 4; ++i_) {                                       \
            const int r_ = w * 32 + i_ * 8 + (lane >> 3);                      \
            GLL((const char*)A  + ((size_t)(m0 + r_) * DD + (k0_)) * 2 + srcoff,\
                (char*)AsB[bufi] + w * 4096 + i_ * 1024);                      \
            GLL((const char*)Bt + ((size_t)(n0 + r_) * DD + (k0_)) * 2 + srcoff,\
                (char*)BsB[bufi] + w * 4096 + i_ * 1024);                      \
        }                                                                      \
    } while (0)

    f32x4 acc[4][4];
    #pragma unroll
    for (int m = 0; m < 4; ++m)
        #pragma unroll
        for (int n = 0; n < 4; ++n) acc[m][n] = (f32x4){0.f, 0.f, 0.f, 0.f};

    GSTAGE(0, 0);
    __syncthreads();

    int cur = 0;
    #pragma unroll 1
    for (int k0 = 0; k0 < DD; k0 += 64) {
        if (k0 + 64 < DD) GSTAGE(k0 + 64, cur ^ 1);

        #pragma unroll
        for (int s = 0; s < 2; ++s) {
            short8v af[4], bf[4];
            #pragma unroll
            for (int m = 0; m < 4; ++m)
                af[m] = *(const short8v*)((const char*)AsB[cur] +
                         SWZ(wr * 64 + m * 16 + lc, s * 64 + lr * 16));
            #pragma unroll
            for (int n = 0; n < 4; ++n)
                bf[n] = *(const short8v*)((const char*)BsB[cur] +
                         SWZ(wc * 64 + n * 16 + lc, s * 64 + lr * 16));
            #pragma unroll
            for (int m = 0; m < 4; ++m)
                #pragma unroll
                for (int n = 0; n < 4; ++n)
                    acc[m][n] = __builtin_amdgcn_mfma_f32_16x16x32_bf16(
                        af[m], bf[n], acc[m][n], 0, 0, 0);
        }

        __syncthreads();   // drains prefetch; all waves done reading buf[cur]
        cur ^= 1;
    }
#undef GSTAGE

    #pragma unroll
    for (int n = 0; n < 4; ++n) {
        const int ng = n0 + wc * 64 + n * 16 + lc;
        const float bv = bias[ng];
        #pragma unroll
        for (int m = 0; m < 4; ++m) {
            const int mg0 = m0 + wr * 64 + m * 16 + lr * 4;
            if (mode == 2) {
                const int bb = mg0 >> 11, tp = mg0 & 2047;
                const int h = ng >> 6, d = ng & 63;
                const size_t idx = (size_t)(bb * HH + h) * (TT * DHH)
                                 + (tp >> 6) * 4096 + ((tp >> 3) & 7) * 512
                                 + d * 8 + (tp & 7);
                union { u16 s[4]; uint2 u; } o;
                #pragma unroll
                for (int r = 0; r < 4; ++r) o.s[r] = f2bf(acc[m][n][r] + bv);
                *(uint2*)&oVt[idx] = o.u;
            } else if (mode == 1) {
                const int h = ng >> 6, d = ng & 63;
                #pragma unroll
                for (int r = 0; r < 4; ++r) {
                    const int mg = mg0 + r;
                    const int bb = mg >> 11, tp = mg & 2047;
                    oK[(size_t)(bb * HH + h) * (TT * DHH)
                       + (tp >> 6) * 4096 + (d >> 3) * 512 + (tp & 63) * 8 + (d & 7)] =
                        f2bf(acc[m][n][r] + bv);
                }
            } else {
                const int h = ng >> 6, d = ng & 63;
                #pragma unroll
                for (int r = 0; r < 4; ++r) {
                    const int mg = mg0 + r;
                    const int bb = mg >> 11, tp = mg & 2047;
                    oQ[((size_t)(bb * HH + h) * TT + tp) * DHH + d] =
                        f2bf((acc[m][n][r] + bv) * QSC);
                }
            }
        }
    }
}

// ---------------------------------------------------------------------------
// Output projection GEMM, 64x128 tiles (R12-proven). XCD swizzle (384%8==0).
// ---------------------------------------------------------------------------
__global__ __launch_bounds__(256) void gemm_out64(
    const u16* __restrict__ A, const u16* __restrict__ Bt,
    const float* __restrict__ bias, float* __restrict__ oF)
{
    const int lin = blockIdx.x;
    const int cpx = gridDim.x >> 3;                 // 48
    const int swz = (lin & 7) * cpx + (lin >> 3);
    const int m0 = (swz / 6) * 64;                  // 64 m-tiles
    const int n0 = (swz % 6) * 128;

    __shared__ __attribute__((aligned(16))) unsigned char AsB[2][8192];
    __shared__ __attribute__((aligned(16))) unsigned char BsB[2][16384];

    const int tid = threadIdx.x, lane = tid & 63, w = tid >> 6;
    const int wr = w >> 1, wc = w & 1;
    const int lr = lane >> 4, lc = lane & 15;
    const int srcoff = 16 * ((lane & 7) ^ (lane >> 3));

#define GSTAGE(k0_, bufi) do {                                                 \
        _Pragma("unroll")                                                      \
        for (int i_ = 0; i_ < 2; ++i_) {                                       \
            const int ra_ = w * 16 + i_ * 8 + (lane >> 3);                     \
            GLL((const char*)A  + ((size_t)(m0 + ra_) * DD + (k0_)) * 2 + srcoff,\
                (char*)AsB[bufi] + w * 2048 + i_ * 1024);                      \
        }                                                                      \
        _Pragma("unroll")                                                      \
        for (int i_ = 0; i_ < 4; ++i_) {                                       \
            const int rb_ = w * 32 + i_ * 8 + (lane >> 3);                     \
            GLL((const char*)Bt + ((size_t)(n0 + rb_) * DD + (k0_)) * 2 + srcoff,\
                (char*)BsB[bufi] + w * 4096 + i_ * 1024);                      \
        }                                                                      \
    } while (0)

    f32x4 acc[2][4];
    #pragma unroll
    for (int m = 0; m < 2; ++m)
        #pragma unroll
        for (int n = 0; n < 4; ++n) acc[m][n] = (f32x4){0.f, 0.f, 0.f, 0.f};

    GSTAGE(0, 0);
    __syncthreads();

    int cur = 0;
    #pragma unroll 1
    for (int k0 = 0; k0 < DD; k0 += 64) {
        if (k0 + 64 < DD) GSTAGE(k0 + 64, cur ^ 1);

        #pragma unroll
        for (int s = 0; s < 2; ++s) {
            short8v af[2], bf[4];
            #pragma unroll
            for (int m = 0; m < 2; ++m)
                af[m] = *(const short8v*)((const char*)AsB[cur] +
                         SWZ(wr * 32 + m * 16 + lc, s * 64 + lr * 16));
            #pragma unroll
            for (int n = 0; n < 4; ++n)
                bf[n] = *(const short8v*)((const char*)BsB[cur] +
                         SWZ(wc * 64 + n * 16 + lc, s * 64 + lr * 16));
            #pragma unroll
            for (int m = 0; m < 2; ++m)
                #pragma unroll
                for (int n = 0; n < 4; ++n)
                    acc[m][n] = __builtin_amdgcn_mfma_f32_16x16x32_bf16(
                        af[m], bf[n], acc[m][n], 0, 0, 0);
        }

        __syncthreads();
        cur ^= 1;
    }
#undef GSTAGE

    #pragma unroll
    for (int n = 0; n < 4; ++n) {
        const int ng = n0 + wc * 64 + n * 16 + lc;
        const float bv = bias[ng];
        #pragma unroll
        for (int m = 0; m < 2; ++m) {
            const int mg0 = m0 + wr * 32 + m * 16 + lr * 4;
            #pragma unroll
            for (int r = 0; r < 4; ++r)
                oF[(size_t)(mg0 + r) * DD + ng] = acc[m][n][r] + bv;
        }
    }
}

// ---------------------------------------------------------------------------
// KV-split MFMA flash attention partial, fixed m=0 softmax (R9/R12 exact
// body: 92 VGPR, 2 blocks/CU, one-shot 64KB chunk staging, ONE barrier).
// grid = 864 = 36 LPT slots * 24 bh; bid%24 = bh -> per-bh XCD affinity.
// ---------------------------------------------------------------------------
__global__ __launch_bounds__(512) void attn_fwd(
    const u16* __restrict__ qb, const u16* __restrict__ kbf,
    const u16* __restrict__ vtb, u16* __restrict__ partO,
    float* __restrict__ partL)
{
    __shared__ __attribute__((aligned(16))) unsigned char smem[65536];
    // K tile t @ t*8192 ; V tile t @ 32768 + t*8192

    const int bid = blockIdx.x;
    const int sp = bid / 24;
    const int bh = bid - sp * 24;
    const int qt = SLOT_QT[sp], c = SLOT_C[sp];
    const int kts = c * 4;

    const int tid = threadIdx.x, lane = tid & 63, w = tid >> 6;   // w 0..7
    const int l31 = lane & 31, hi = lane >> 5;

    // stage the whole chunk: 4 K tiles + 4 V tiles, 1 GLL each per thread
    {
        const char* kbase = (const char*)kbf + (size_t)bh * (TT * DHH * 2)
                          + (size_t)kts * 8192;
        const char* vbase = (const char*)vtb + (size_t)bh * (TT * DHH * 2)
                          + (size_t)kts * 8192;
        const int off = w * 1024;
        #pragma unroll
        for (int t = 0; t < 4; ++t) {
            GLL(kbase + t * 8192 + off + lane * 16,
                (char*)smem + t * 8192 + off);
            GLL(vbase + t * 8192 + off + lane * 16,
                (char*)smem + 32768 + t * 8192 + off);
        }
    }

    // Q fragments (pre-scaled at projection): row = qt*256 + w*32 + l31
    short8v aq[4];
    {
        const u16* qrow = qb + ((size_t)bh * TT + qt * 256 + w * 32 + l31) * DHH;
        #pragma unroll
        for (int s4 = 0; s4 < 4; ++s4)
            aq[s4] = *(const short8v*)(qrow + s4 * 16 + hi * 8);
    }

    f32x16 accO[2];
    #pragma unroll
    for (int i = 0; i < 16; ++i) { accO[0][i] = 0.f; accO[1][i] = 0.f; }
    float lreg = 0.f;

    __syncthreads();   // single barrier: drains GLLs, LDS read-only afterwards

    const int qmin = qt * 256 + w * 32;
    #pragma unroll
    for (int t = 0; t < 4; ++t) {
        const int kt = kts + t;
        if (kt * 64 <= qmin + 31) {   // wave has >=1 unmasked key in this tile
            const unsigned char* Kb = smem + t * 8192;
            const unsigned char* Vb = smem + 32768 + t * 8192;

            // S^T = K * Q^T (scores in log2 units via Q prescale)
            f32x16 st[2];
            #pragma unroll
            for (int i = 0; i < 16; ++i) { st[0][i] = 0.f; st[1][i] = 0.f; }
            __builtin_amdgcn_s_setprio(1);
            #pragma unroll
            for (int s4 = 0; s4 < 4; ++s4) {
                #pragma unroll
                for (int kf = 0; kf < 2; ++kf) {
                    const short8v ak = *(const short8v*)(Kb +
                        (s4 * 2 + hi) * 1024 + (kf * 32 + l31) * 16);
                    st[kf] = __builtin_amdgcn_mfma_f32_32x32x16_bf16(ak, aq[s4], st[kf], 0, 0, 0);
                }
            }
            __builtin_amdgcn_s_setprio(0);

            if (kt * 64 + 63 > qmin) {   // partial-diagonal tile: mask
                const int rowrel = qmin + l31 - kt * 64;   // q col = l31
                #pragma unroll
                for (int kf = 0; kf < 2; ++kf)
                    #pragma unroll
                    for (int reg = 0; reg < 16; ++reg) {
                        const int kloc = kf * 32 + (reg & 3) + 8 * (reg >> 2) + 4 * hi;
                        if (kloc > rowrel) st[kf][reg] = -3.0e38f;
                    }
            }

            // p = exp2(s); tree-summed row sum (no max tracking)
            float rs4[4] = {0.f, 0.f, 0.f, 0.f};
            #pragma unroll
            for (int kf = 0; kf < 2; ++kf)
                #pragma unroll
                for (int reg = 0; reg < 16; ++reg) {
                    const float p = fexp2(st[kf][reg]);
                    st[kf][reg] = p;
                    rs4[reg & 3] += p;
                }
            float rs = (rs4[0] + rs4[1]) + (rs4[2] + rs4[3]);
            {   // cross-half add via permlane32_swap (no ds_bpermute)
                u32 a, b;
                union { float f; u32 u; } cv; cv.f = rs;
                a = cv.u; b = cv.u;
                asm volatile("v_permlane32_swap_b32 %0, %1" : "+v"(a), "+v"(b));
                union { u32 u; float f; } pa, pb; pa.u = a; pb.u = b;
                const float partner = hi ? pa.f : pb.f;
                rs += partner;
            }
            lreg += rs;

            // pack P -> A-frags via cvt_pk + permlane32_swap, accumulate PV
            __builtin_amdgcn_s_setprio(1);
            #pragma unroll
            for (int ka = 0; ka < 4; ++ka) {
                const int kf = ka >> 1;
                const int rb0 = 4 * ((ka & 1) * 2);       // hi_dst = 0 reg block
                const int rb1 = 4 * ((ka & 1) * 2 + 1);   // hi_dst = 1 reg block
                u32 P0 = pkpair(st[kf][rb0 + 0], st[kf][rb0 + 1]);
                u32 P1 = pkpair(st[kf][rb0 + 2], st[kf][rb0 + 3]);
                u32 Q0 = pkpair(st[kf][rb1 + 0], st[kf][rb1 + 1]);
                u32 Q1 = pkpair(st[kf][rb1 + 2], st[kf][rb1 + 3]);
                asm volatile("v_permlane32_swap_b32 %0, %1" : "+v"(P0), "+v"(Q0));
                asm volatile("v_permlane32_swap_b32 %0, %1" : "+v"(P1), "+v"(Q1));
                union { u32 wd[4]; short8v v; } u;
                u.wd[0] = P0; u.wd[1] = P1; u.wd[2] = Q0; u.wd[3] = Q1;
                #pragma unroll
                for (int dc = 0; dc < 2; ++dc) {
                    const short8v bv = *(const short8v*)(Vb +
                        (ka * 2 + hi) * 1024 + (dc * 32 + l31) * 16);
                    accO[dc] = __builtin_amdgcn_mfma_f32_32x32x16_bf16(u.v, bv, accO[dc], 0, 0, 0);
                }
            }
            __builtin_amdgcn_s_setprio(0);
        }
    }

    // store partials (O bf16 unnormalized, l f32)
    const int gslot = bh * NSLOT + sp;
    if (hi == 0)
        partL[(size_t)gslot * 256 + w * 32 + l31] = lreg;
    u16* po = partO + (size_t)gslot * 16384;
    #pragma unroll
    for (int reg = 0; reg < 16; ++reg) {
        const int qrow = (reg & 3) + 8 * (reg >> 2) + 4 * hi;
        #pragma unroll
        for (int dc = 0; dc < 2; ++dc)
            po[(w * 32 + qrow) * 64 + dc * 32 + l31] = f2bf(accO[dc][reg]);
    }
}

// ---------------------------------------------------------------------------
// Merge KV-split partials (plain sums), normalize, write ctx bf16 [b*t][768].
// grid = 768 (q64-quarter x bh), 256 thr = 3 blocks/CU (R11-proven).
// Thread: q = tid>>2 (64 rows), dg = tid&3 (16 cols).
// ---------------------------------------------------------------------------
__global__ __launch_bounds__(256) void attn_combine(
    const u16* __restrict__ partO, const float* __restrict__ partL,
    u16* __restrict__ ctx)
{
    const int bid = blockIdx.x;
    const int q64 = bid / 24, bh = bid - q64 * 24;
    const int b = bh / HH, h = bh - b * HH;
    const int qt = q64 >> 2;              // 256-row tile index
    const int sub = q64 & 3;              // 64-row quarter within it
    const int tid = threadIdx.x, q = tid >> 2, dg = tid & 3;
    const int prow = sub * 64 + q;        // row within the 256-row tile

    float lsum = 0.f;
    float acc[16];
    #pragma unroll
    for (int j = 0; j < 16; ++j) acc[j] = 0.f;

#define ACCUM(gs) do {                                                         \
        lsum += partL[(size_t)(gs) * 256 + prow];                              \
        const u16* po_ = partO + (size_t)(gs) * 16384 + prow * 64 + dg * 16;   \
        _Pragma("unroll")                                                      \
        for (int v_ = 0; v_ < 2; ++v_) {                                       \
            const uint4 pk = *(const uint4*)(po_ + v_ * 8);                    \
            acc[v_*8+0] += bflo(pk.x); acc[v_*8+1] += bfhi(pk.x);              \
            acc[v_*8+2] += bflo(pk.y); acc[v_*8+3] += bfhi(pk.y);              \
            acc[v_*8+4] += bflo(pk.z); acc[v_*8+5] += bfhi(pk.z);              \
            acc[v_*8+6] += bflo(pk.w); acc[v_*8+7] += bfhi(pk.w);              \
        }                                                                      \
    } while (0)

    const int basef = bh * NSLOT + BASEF[qt];
    #pragma unroll 1
    for (int cc = 0; cc < qt; ++cc) ACCUM(basef + cc);
    ACCUM(bh * NSLOT + (35 - qt));        // diagonal chunk
#undef ACCUM

    const float inv = 1.f / lsum;
    u16* dst = ctx + (size_t)(b * TT + qt * 256 + prow) * DD + h * 64 + dg * 16;
    #pragma unroll
    for (int v = 0; v < 2; ++v) {
        uint4 o;
        o.x = pkpair(acc[v*8+0] * inv, acc[v*8+1] * inv);
        o.y = pkpair(acc[v*8+2] * inv, acc[v*8+3] * inv);
        o.z = pkpair(acc[v*8+4] * inv, acc[v*8+5] * inv);
        o.w = pkpair(acc[v*8+6] * inv, acc[v*8+7] * inv);
        *(uint4*)(dst + v * 8) = o;
    }
}

extern "C" void kernel_launch(void* const* d_in, const int* in_sizes, int n_in,
                              void* d_out, int out_size, void* d_ws, size_t ws_size,
                              hipStream_t stream) {
    (void)in_sizes; (void)n_in; (void)out_size; (void)ws_size;
    const float* x  = (const float*)d_in[0];
    const float* Wq = (const float*)d_in[1];
    const float* bq = (const float*)d_in[2];
    const float* Wk = (const float*)d_in[3];
    const float* bk = (const float*)d_in[4];
    const float* Wv = (const float*)d_in[5];
    const float* bv = (const float*)d_in[6];
    const float* Wo = (const float*)d_in[7];
    const float* bo = (const float*)d_in[8];
    float* out = (float*)d_out;

    u16* xb    = (u16*)d_ws;
    u16* WtQ   = xb + (size_t)MM * DD;
    u16* WtK   = WtQ + (size_t)DD * DD;
    u16* WtV   = WtK + (size_t)DD * DD;
    u16* WtO   = WtV + (size_t)DD * DD;
    u16* qbuf  = WtO + (size_t)DD * DD;      // [bh][t][d] row-major, pre-scaled
    u16* kbuf  = qbuf + (size_t)MM * DD;     // [bh][kt][j][krow][e] subtiled
    u16* vtbuf = kbuf + (size_t)MM * DD;     // [bh][kt][j][d][e]   subtiled
    u16* ctxb  = vtbuf + (size_t)MM * DD;    // [b*t][768]
    u16* pO    = ctxb + (size_t)MM * DD;     // 864 slots * 16384 bf16
    float* pL  = (float*)(pO + (size_t)24 * NSLOT * 16384);  // 864 * 256 f32

    prep<<<dim3(3648), 256, 0, stream>>>(x, xb, Wq, Wk, Wv, Wo, WtQ, WtK, WtV, WtO);
    gemm_bt<<<dim3(576), 256, 0, stream>>>(xb, WtQ, WtK, WtV, bq, bk, bv,
                                           qbuf, kbuf, vtbuf);
    attn_fwd<<<dim3(24 * NSLOT), 512, 0, stream>>>(qbuf, kbuf, vtbuf, pO, pL);
    attn_combine<<<dim3(768), 256, 0, stream>>>(pO, pL, ctxb);
    gemm_out64<<<dim3(384), 256, 0, stream>>>(ctxb, WtO, bo, out);
}